// Round 10
// baseline (156.450 us; speedup 1.0000x reference)
//
#include <hip/hip_runtime.h>

// Deformable Conv2D (B=8, C=256, H=W=64, K=3, s=1, p=1) + ReLU via fp16 MFMA.
//
// Round 9: tap-outer fat phases (9 barriers), strict FIFO-ordered issue.
//  - per tap k: stage 64pix x 256ch fp16 B-tile (16 cell-gathers/lane,
//    4-pair rotation) -> barrier -> 64 MFMAs (8 cc x 8) with 2-ahead A regs
//  - issue order == consume order across the whole loop => every consume is
//    a counted vmcnt(N); gathers and A-loads never false-wait on each other
//  - btile[2][64][256] double-buffer: stage(k+1) overlaps other waves' mfma(k)
//  - 16B-slot XOR swizzle (slot ^ (pix&7)): b128 reads conflict-free
//  - raw lgkmcnt(0)+s_barrier: globals stay in flight across barriers

#define B_   8
#define C_   256
#define H_   64
#define W_   64
#define K2_  9
#define HW_  4096

typedef __fp16 f16x2 __attribute__((ext_vector_type(2)));
typedef __fp16 f16x8 __attribute__((ext_vector_type(8)));
typedef float  f32x4 __attribute__((ext_vector_type(4)));

static __device__ __forceinline__ f16x2 u2h(unsigned u) {
    union { unsigned u; f16x2 h; } v; v.u = u; return v.h;
}
static __device__ __forceinline__ unsigned h2u(f16x2 h) {
    union { unsigned u; f16x2 h; } v; v.h = h; return v.u;
}

// ---- weights -> fp16, MFMA A-fragment lane order (validated r6-r8) ----
__global__ __launch_bounds__(256) void wpack_kernel(
    const float* __restrict__ w, unsigned short* __restrict__ wA) {
    const int t = blockIdx.x * 256 + threadIdx.x;
    if (t >= C_ * C_ * K2_) return;
    const int k = t % 9;
    const int c = (t / 9) & 255;
    const int o = t / (9 * 256);
    const int cc = c >> 5, lg = (c >> 3) & 3, e = c & 7;
    const int t16 = o >> 4, lr = o & 15;
    const int dst = e + 8 * (lr + 16 * (lg + 4 * (t16 + 16 * (cc + 8 * k))));
    const __fp16 h = (__fp16)w[t];
    unsigned short us;
    __builtin_memcpy(&us, &h, 2);
    wA[dst] = us;
}

// ---- x -> fp16 2x2 quads, channel-paired 16B cells (validated r6-r8) ----
__global__ __launch_bounds__(256) void xq2pack_kernel(
    const float* __restrict__ x, uint4* __restrict__ xq2) {
    const int t = blockIdx.x * 256 + threadIdx.x;     // B*C/2*1024 threads
    const int pix4 = (t & 1023) * 4;
    const int gc2  = t >> 10;
    const int y  = pix4 >> 6;
    const int x0 = pix4 & 63;
    const int rb = (y == 63) ? 0 : W_;
    const int nx = (x0 == 60) ? 3 : 4;
    const float* p0 = x + (size_t)(2 * gc2) * HW_ + pix4;
    const float* p1 = p0 + HW_;
    const float4 A0 = *(const float4*)p0;        const float nA0 = p0[nx];
    const float4 B0 = *(const float4*)(p0 + rb); const float nB0 = p0[rb + nx];
    const float4 A1 = *(const float4*)p1;        const float nA1 = p1[nx];
    const float4 B1 = *(const float4*)(p1 + rb); const float nB1 = p1[rb + nx];
    const float a0[5] = {A0.x, A0.y, A0.z, A0.w, nA0};
    const float b0[5] = {B0.x, B0.y, B0.z, B0.w, nB0};
    const float a1[5] = {A1.x, A1.y, A1.z, A1.w, nA1};
    const float b1[5] = {B1.x, B1.y, B1.z, B1.w, nB1};
    uint4* dst = xq2 + (size_t)gc2 * HW_ + pix4;
#pragma unroll
    for (int i = 0; i < 4; ++i) {
        uint4 cell;
        cell.x = h2u(__builtin_amdgcn_cvt_pkrtz(a0[i], a0[i + 1]));
        cell.y = h2u(__builtin_amdgcn_cvt_pkrtz(b0[i], b0[i + 1]));
        cell.z = h2u(__builtin_amdgcn_cvt_pkrtz(a1[i], a1[i + 1]));
        cell.w = h2u(__builtin_amdgcn_cvt_pkrtz(b1[i], b1[i + 1]));
        dst[i] = cell;
    }
}

// MODE 0: pipelined 16B cell gathers. MODE 1: f32 corner loads (fallback).
template<int MODE>
__global__ __launch_bounds__(512, 4) void deform_main(
    const float* __restrict__ x, const uint4* __restrict__ xq2,
    const float* __restrict__ offset, const unsigned short* __restrict__ wA,
    float* __restrict__ out)
{
    const int bid = blockIdx.x;
    const int b = bid & 7, ho = bid >> 3;     // batch -> XCD
    const int tid = threadIdx.x;
    const int lane = tid & 63;                // staging pixel; MFMA lane
    const int wv   = tid >> 6;                // wave 0..7
    const int lr = lane & 15, lg = (lane >> 4) & 3;
    const int wvh = wv >> 1, wvl = wv & 1;

    __shared__ unsigned short gaddr[K2_][W_];           // quad base ys*64+xs
    __shared__ uint2 gw2[K2_][W_];                      // fp16 weight pairs
    __shared__ alignas(16) unsigned short btile[2][W_][256];  // 64 KB dbuf

    // ---- geometry: 9 taps x 64 pixels (validated r4-r8) ----
    for (int e = tid; e < K2_ * W_; e += 512) {
        const int k = e >> 6, wo = e & 63;
        const float offy = offset[((b * 18 + 2 * k    ) * H_ + ho) * W_ + wo];
        const float offx = offset[((b * 18 + 2 * k + 1) * H_ + ho) * W_ + wo];
        const float py = (float)(k / 3 + ho - 1) + offy;
        const float px = (float)(k % 3 + wo - 1) + offx;
        const float y0f = floorf(py), x0f = floorf(px);
        const int   y0 = (int)y0f,   x0 = (int)x0f;
        const float fy = py - y0f,   fx = px - x0f;
        const float wy0 = (y0 >= 0  && y0 < H_)     ? 1.f - fy : 0.f;
        const float wy1 = (y0 >= -1 && y0 < H_ - 1) ? fy       : 0.f;
        const float wx0 = (x0 >= 0  && x0 < W_)     ? 1.f - fx : 0.f;
        const float wx1 = (x0 >= -1 && x0 < W_ - 1) ? fx       : 0.f;
        const int ys = min(max(y0, 0), H_ - 2);
        const int xs = min(max(x0, 0), W_ - 2);
        const float qy0 = (ys == y0 ? wy0 : 0.f) + (ys == y0 + 1 ? wy1 : 0.f);
        const float qy1 = (ys + 1 == y0 ? wy0 : 0.f) + (ys + 1 == y0 + 1 ? wy1 : 0.f);
        const float qx0 = (xs == x0 ? wx0 : 0.f) + (xs == x0 + 1 ? wx1 : 0.f);
        const float qx1 = (xs + 1 == x0 ? wx0 : 0.f) + (xs + 1 == x0 + 1 ? wx1 : 0.f);
        gaddr[k][wo] = (unsigned short)(ys * W_ + xs);
        gw2[k][wo] = make_uint2(
            h2u(__builtin_amdgcn_cvt_pkrtz(qy0 * qx0, qy0 * qx1)),
            h2u(__builtin_amdgcn_cvt_pkrtz(qy1 * qx0, qy1 * qx1)));
    }
    __syncthreads();

    f32x4 acc[2][4];
#pragma unroll
    for (int m = 0; m < 2; ++m)
#pragma unroll
        for (int n = 0; n < 4; ++n) acc[m][n] = (f32x4)0.f;

    const __fp16* wAh = (const __fp16*)wA;

    if constexpr (MODE == 0) {
        // wave wv's cell planes: b*(C/2) + cc*16 + wv*2 + {0,1}
        const uint4* xqb = xq2 + ((size_t)(b * (C_ / 2)) + wv * 2) * HW_;
        uint4 qa[4], qb[4];        // gather rotation (4 cc-pairs in flight)
        f16x8 afA[3], afB[3];      // A-frag rotation (2-ahead)

        // prologue: PAIR(k=0, cc=0..3)
        {
            const int a0 = gaddr[0][lane];
#pragma unroll
            for (int j = 0; j < 4; ++j) {
                const uint4* pp = xqb + (size_t)(j * 16) * HW_ + a0;
                qa[j] = pp[0];
                qb[j] = pp[HW_];
            }
        }

        for (int k = 0; k < K2_; ++k) {
            const int bp = k & 1;
            // ================= STAGE(k) =================
            const int a = gaddr[k][lane];
            const uint2 wp = gw2[k][lane];
            const f16x2 wt = u2h(wp.x), wbm = u2h(wp.y);
#pragma unroll
            for (int cc = 0; cc < 8; ++cc) {
                const uint4 q0 = qa[cc & 3];   // counted vmcnt wait
                const uint4 q1 = qb[cc & 3];
                if (cc < 4) {                  // refill pair cc+4
                    const uint4* pp = xqb + (size_t)((cc + 4) * 16) * HW_ + a;
                    qa[cc & 3] = pp[0];
                    qb[cc & 3] = pp[HW_];
                }
                const float vs0 = __builtin_amdgcn_fdot2(u2h(q0.y), wbm,
                    __builtin_amdgcn_fdot2(u2h(q0.x), wt, 0.f, false), false);
                const float vs1 = __builtin_amdgcn_fdot2(u2h(q0.w), wbm,
                    __builtin_amdgcn_fdot2(u2h(q0.z), wt, 0.f, false), false);
                const float vs2 = __builtin_amdgcn_fdot2(u2h(q1.y), wbm,
                    __builtin_amdgcn_fdot2(u2h(q1.x), wt, 0.f, false), false);
                const float vs3 = __builtin_amdgcn_fdot2(u2h(q1.w), wbm,
                    __builtin_amdgcn_fdot2(u2h(q1.z), wt, 0.f, false), false);
                const unsigned pk0 = h2u(__builtin_amdgcn_cvt_pkrtz(vs0, vs1));
                const unsigned pk1 = h2u(__builtin_amdgcn_cvt_pkrtz(vs2, vs3));
                const int slot = (cc * 4 + wvh) ^ (lane & 7);
                *(uint2*)&btile[bp][lane][slot * 8 + wvl * 4] =
                    make_uint2(pk0, pk1);
            }
            // A(k, 0..1) issued last in stage (consumed first in mfma)
            {
                const __fp16* ap0 = wAh +
                    (((size_t)(k * 8 + 0) * 16 + wv * 2) * 64 + lane) * 8;
                afA[0] = *(const f16x8*)ap0;
                afB[0] = *(const f16x8*)(ap0 + 512);
                const __fp16* ap1 = wAh +
                    (((size_t)(k * 8 + 1) * 16 + wv * 2) * 64 + lane) * 8;
                afA[1] = *(const f16x8*)ap1;
                afB[1] = *(const f16x8*)(ap1 + 512);
            }
            asm volatile("s_waitcnt lgkmcnt(0)" ::: "memory");
            __builtin_amdgcn_s_barrier();

            // ================= MFMA(k) =================
#pragma unroll
            for (int cc = 0; cc < 8; ++cc) {
                const f16x8 a0 = afA[cc % 3];
                const f16x8 a1 = afB[cc % 3];
                if (cc < 6) {                  // A(k, cc+2), 2-ahead
                    const __fp16* ap = wAh +
                        (((size_t)(k * 8 + cc + 2) * 16 + wv * 2) * 64 + lane) * 8;
                    afA[(cc + 2) % 3] = *(const f16x8*)ap;
                    afB[(cc + 2) % 3] = *(const f16x8*)(ap + 512);
                }
                if (cc == 6 && k < K2_ - 1) {  // PAIR(k+1, 0..3) after all A issues
                    const int an = gaddr[k + 1][lane];
#pragma unroll
                    for (int j = 0; j < 4; ++j) {
                        const uint4* pp = xqb + (size_t)(j * 16) * HW_ + an;
                        qa[j] = pp[0];
                        qb[j] = pp[HW_];
                    }
                }
#pragma unroll
                for (int nt = 0; nt < 4; ++nt) {
                    const int pix = nt * 16 + lr;
                    const int slot = (cc * 4 + lg) ^ (lr & 7);
                    const f16x8 bv =
                        *(const f16x8*)&btile[bp][pix][slot * 8];
                    acc[0][nt] = __builtin_amdgcn_mfma_f32_16x16x32_f16(
                        a0, bv, acc[0][nt], 0, 0, 0);
                    acc[1][nt] = __builtin_amdgcn_mfma_f32_16x16x32_f16(
                        a1, bv, acc[1][nt], 0, 0, 0);
                }
            }
            // no barrier: stage(k+1) writes btile[bp^1]
        }
    } else {
        // fallback: direct f32 corner loads, plain barriers (correctness only)
        const float* xfb = x + (size_t)(b * C_) * HW_;
        for (int k = 0; k < K2_; ++k) {
            const int bp = k & 1;
            const int a = gaddr[k][lane];
            const uint2 wp = gw2[k][lane];
            const f16x2 wt = u2h(wp.x), wbm = u2h(wp.y);
            const float w00 = (float)wt.x, w01 = (float)wt.y;
            const float w10 = (float)wbm.x, w11 = (float)wbm.y;
#pragma unroll
            for (int cc = 0; cc < 8; ++cc) {
                float vs[4];
#pragma unroll
                for (int j = 0; j < 4; ++j) {
                    const float* pl = xfb + (size_t)(cc * 32 + wv * 4 + j) * HW_;
                    vs[j] = w00 * pl[a] + w01 * pl[a + 1]
                          + w10 * pl[a + W_] + w11 * pl[a + W_ + 1];
                }
                const unsigned pk0 = h2u(__builtin_amdgcn_cvt_pkrtz(vs[0], vs[1]));
                const unsigned pk1 = h2u(__builtin_amdgcn_cvt_pkrtz(vs[2], vs[3]));
                const int slot = (cc * 4 + wvh) ^ (lane & 7);
                *(uint2*)&btile[bp][lane][slot * 8 + wvl * 4] =
                    make_uint2(pk0, pk1);
            }
            __syncthreads();
#pragma unroll
            for (int cc = 0; cc < 8; ++cc) {
                const __fp16* ap = wAh +
                    (((size_t)(k * 8 + cc) * 16 + wv * 2) * 64 + lane) * 8;
                const f16x8 a0 = *(const f16x8*)ap;
                const f16x8 a1 = *(const f16x8*)(ap + 512);
#pragma unroll
                for (int nt = 0; nt < 4; ++nt) {
                    const int pix = nt * 16 + lr;
                    const int slot = (cc * 4 + lg) ^ (lr & 7);
                    const f16x8 bv =
                        *(const f16x8*)&btile[bp][pix][slot * 8];
                    acc[0][nt] = __builtin_amdgcn_mfma_f32_16x16x32_f16(
                        a0, bv, acc[0][nt], 0, 0, 0);
                    acc[1][nt] = __builtin_amdgcn_mfma_f32_16x16x32_f16(
                        a1, bv, acc[1][nt], 0, 0, 0);
                }
            }
            __syncthreads();
        }
    }

    // ---- epilogue: ReLU + store (C/D: col=lane&15 -> pixel, row=lg*4+r -> oc)
    const size_t ob = (size_t)b * C_ * HW_ + (size_t)ho * W_;
#pragma unroll
    for (int mt = 0; mt < 2; ++mt) {
        const int o0 = wv * 32 + mt * 16 + lg * 4;
#pragma unroll
        for (int nt = 0; nt < 4; ++nt) {
            const int wo = nt * 16 + lr;
#pragma unroll
            for (int r = 0; r < 4; ++r)
                out[ob + (size_t)(o0 + r) * HW_ + wo] =
                    fmaxf(acc[mt][nt][r], 0.f);
        }
    }
}

extern "C" void kernel_launch(void* const* d_in, const int* in_sizes, int n_in,
                              void* d_out, int out_size, void* d_ws, size_t ws_size,
                              hipStream_t stream) {
    const float* x      = (const float*)d_in[0];
    const float* offset = (const float*)d_in[1];
    const float* weight = (const float*)d_in[2];
    float* out          = (float*)d_out;

    const size_t wA_bytes = (size_t)K2_ * C_ * C_ * 2;        // 1.18 MB
    const size_t xq_off   = wA_bytes;                         // 16B-aligned
    const size_t ncell    = (size_t)B_ * (C_ / 2) * HW_;      // 4.19M cells
    const size_t need     = xq_off + ncell * 16;              // ~68.3 MB

    unsigned short* wAp = (unsigned short*)d_ws;
    uint4*          xqp = (uint4*)((char*)d_ws + xq_off);

    wpack_kernel<<<(C_ * C_ * K2_ + 255) / 256, 256, 0, stream>>>(weight, wAp);

    if (ws_size >= need) {
        xq2pack_kernel<<<(int)(ncell / 4 / 256), 256, 0, stream>>>(x, xqp);
        deform_main<0><<<512, 512, 0, stream>>>(x, xqp, offset, wAp, out);
    } else {
        deform_main<1><<<512, 512, 0, stream>>>(x, xqp, offset, wAp, out);
    }
}

// Round 11
// 129.178 us; speedup vs baseline: 1.2111x; 1.2111x over previous
//
#include <hip/hip_runtime.h>

// Deformable Conv2D (B=8, C=256, H=W=64, K=3, s=1, p=1) + ReLU via fp16 MFMA.
//
// Round 10: r8 structure (cc-outer / tap-inner, proven 45MB FETCH) with
// 4 independent blocks/CU for latency overlap.
//  - 1024 blocks x 256 thr (4 waves): block = (b, ho, half-row of 32 pix),
//    all 256 output channels. LDS ~21KB -> 4 blocks/CU, 4 barrier groups.
//  - per cc: STAGE 9 taps (16B cell gathers, depth-5 rotation, cross-phase
//    hoist of taps 0-4 at MFMA k==8) -> barrier -> MFMA 9x8 with 1-ahead
//    A double-buffer (parity-alternating named arrays, all-static indexing)
//  - strict FIFO issue order == consume order; lgkmcnt(0)-only barriers
//  - r8's proven LDS swizzle (slot ^ pix-bits)

#define B_   8
#define C_   256
#define H_   64
#define W_   64
#define K2_  9
#define HW_  4096

typedef __fp16 f16x2 __attribute__((ext_vector_type(2)));
typedef __fp16 f16x8 __attribute__((ext_vector_type(8)));
typedef float  f32x4 __attribute__((ext_vector_type(4)));

static __device__ __forceinline__ f16x2 u2h(unsigned u) {
    union { unsigned u; f16x2 h; } v; v.u = u; return v.h;
}
static __device__ __forceinline__ unsigned h2u(f16x2 h) {
    union { unsigned u; f16x2 h; } v; v.h = h; return v.u;
}

// ---- weights -> fp16, MFMA A-fragment lane order (validated r6-r9) ----
__global__ __launch_bounds__(256) void wpack_kernel(
    const float* __restrict__ w, unsigned short* __restrict__ wA) {
    const int t = blockIdx.x * 256 + threadIdx.x;
    if (t >= C_ * C_ * K2_) return;
    const int k = t % 9;
    const int c = (t / 9) & 255;
    const int o = t / (9 * 256);
    const int cc = c >> 5, lg = (c >> 3) & 3, e = c & 7;
    const int t16 = o >> 4, lr = o & 15;
    const int dst = e + 8 * (lr + 16 * (lg + 4 * (t16 + 16 * (cc + 8 * k))));
    const __fp16 h = (__fp16)w[t];
    unsigned short us;
    __builtin_memcpy(&us, &h, 2);
    wA[dst] = us;
}

// ---- x -> fp16 2x2 quads, channel-paired 16B cells (validated r6-r9) ----
__global__ __launch_bounds__(256) void xq2pack_kernel(
    const float* __restrict__ x, uint4* __restrict__ xq2) {
    const int t = blockIdx.x * 256 + threadIdx.x;     // B*C/2*1024 threads
    const int pix4 = (t & 1023) * 4;
    const int gc2  = t >> 10;
    const int y  = pix4 >> 6;
    const int x0 = pix4 & 63;
    const int rb = (y == 63) ? 0 : W_;
    const int nx = (x0 == 60) ? 3 : 4;
    const float* p0 = x + (size_t)(2 * gc2) * HW_ + pix4;
    const float* p1 = p0 + HW_;
    const float4 A0 = *(const float4*)p0;        const float nA0 = p0[nx];
    const float4 B0 = *(const float4*)(p0 + rb); const float nB0 = p0[rb + nx];
    const float4 A1 = *(const float4*)p1;        const float nA1 = p1[nx];
    const float4 B1 = *(const float4*)(p1 + rb); const float nB1 = p1[rb + nx];
    const float a0[5] = {A0.x, A0.y, A0.z, A0.w, nA0};
    const float b0[5] = {B0.x, B0.y, B0.z, B0.w, nB0};
    const float a1[5] = {A1.x, A1.y, A1.z, A1.w, nA1};
    const float b1[5] = {B1.x, B1.y, B1.z, B1.w, nB1};
    uint4* dst = xq2 + (size_t)gc2 * HW_ + pix4;
#pragma unroll
    for (int i = 0; i < 4; ++i) {
        uint4 cell;
        cell.x = h2u(__builtin_amdgcn_cvt_pkrtz(a0[i], a0[i + 1]));
        cell.y = h2u(__builtin_amdgcn_cvt_pkrtz(b0[i], b0[i + 1]));
        cell.z = h2u(__builtin_amdgcn_cvt_pkrtz(a1[i], a1[i + 1]));
        cell.w = h2u(__builtin_amdgcn_cvt_pkrtz(b1[i], b1[i + 1]));
        dst[i] = cell;
    }
}

// MODE 0: pipelined 16B cell gathers. MODE 1: f32 corner loads (fallback).
template<int MODE>
__global__ __launch_bounds__(256, 4) void deform_main(
    const float* __restrict__ x, const uint4* __restrict__ xq2,
    const float* __restrict__ offset, const unsigned short* __restrict__ wA,
    float* __restrict__ out)
{
    const int bid = blockIdx.x;
    const int b  = bid & 7;          // batch -> XCD
    const int rh = bid >> 3;         // 0..127
    const int ho = rh >> 1;
    const int hf = rh & 1;           // which 32-pixel half of the row
    const int tid = threadIdx.x;
    const int lane = tid & 63;
    const int wv   = tid >> 6;       // wave 0..3
    const int lr = lane & 15, lg = (lane >> 4) & 3;
    const int pix5 = lane & 31;      // staging pixel (0..31)
    const int ph   = lane >> 5;      // plane-pair half (0/1)

    __shared__ unsigned short gaddr[K2_][32];     // quad base ys*64+xs
    __shared__ uint2 gw2[K2_][32];                // fp16 weight pairs
    __shared__ alignas(16) unsigned short btile[K2_][32][32];  // 18 KB

    // ---- geometry: 9 taps x 32 pixels ----
    for (int e = tid; e < K2_ * 32; e += 256) {
        const int k = e >> 5, w5 = e & 31;
        const int wo = hf * 32 + w5;
        const float offy = offset[((b * 18 + 2 * k    ) * H_ + ho) * W_ + wo];
        const float offx = offset[((b * 18 + 2 * k + 1) * H_ + ho) * W_ + wo];
        const float py = (float)(k / 3 + ho - 1) + offy;
        const float px = (float)(k % 3 + wo - 1) + offx;
        const float y0f = floorf(py), x0f = floorf(px);
        const int   y0 = (int)y0f,   x0 = (int)x0f;
        const float fy = py - y0f,   fx = px - x0f;
        const float wy0 = (y0 >= 0  && y0 < H_)     ? 1.f - fy : 0.f;
        const float wy1 = (y0 >= -1 && y0 < H_ - 1) ? fy       : 0.f;
        const float wx0 = (x0 >= 0  && x0 < W_)     ? 1.f - fx : 0.f;
        const float wx1 = (x0 >= -1 && x0 < W_ - 1) ? fx       : 0.f;
        const int ys = min(max(y0, 0), H_ - 2);
        const int xs = min(max(x0, 0), W_ - 2);
        const float qy0 = (ys == y0 ? wy0 : 0.f) + (ys == y0 + 1 ? wy1 : 0.f);
        const float qy1 = (ys + 1 == y0 ? wy0 : 0.f) + (ys + 1 == y0 + 1 ? wy1 : 0.f);
        const float qx0 = (xs == x0 ? wx0 : 0.f) + (xs == x0 + 1 ? wx1 : 0.f);
        const float qx1 = (xs + 1 == x0 ? wx0 : 0.f) + (xs + 1 == x0 + 1 ? wx1 : 0.f);
        gaddr[k][w5] = (unsigned short)(ys * W_ + xs);
        gw2[k][w5] = make_uint2(
            h2u(__builtin_amdgcn_cvt_pkrtz(qy0 * qx0, qy0 * qx1)),
            h2u(__builtin_amdgcn_cvt_pkrtz(qy1 * qx0, qy1 * qx1)));
    }
    __syncthreads();

    f32x4 acc[4][2];
#pragma unroll
    for (int m = 0; m < 4; ++m)
#pragma unroll
        for (int n = 0; n < 2; ++n) acc[m][n] = (f32x4)0.f;

    const __fp16* wAh = (const __fp16*)wA;
    // per-thread ds-write slot (r8 swizzle): bits 1-2 of slot ^ bits 1-2 of pix
    const int wslot = (wv * 2 + ph) ^ (((pix5 >> 1) & 3) << 1);
    unsigned short* const wdst0 = &btile[0][pix5][wslot * 4];

    if constexpr (MODE == 0) {
        // thread's cell planes: b*(C/2) + cc*16 + wv*4 + ph*2 + {0,1}
        const uint4* xqb = xq2 + ((size_t)(b * (C_ / 2)) + wv * 4 + ph * 2) * HW_;
        uint4 qa[5], qb[5];            // depth-5 tap rotation
        f16x8 afA[4], afB[4];          // A-frag double buffer (phase parity)

        // prologue: taps 0-4 of cc=0
        {
#pragma unroll
            for (int j = 0; j < 5; ++j) {
                const int a = gaddr[j][pix5];
                qa[j] = xqb[a];
                qb[j] = xqb[HW_ + a];
            }
        }

        // ---- STAGE(cc): 9 taps; issues af(cc,0) into dst at end iff first ----
        auto stage = [&](int cc, f16x8 (&af0dst)[4], bool issueA0) {
            const uint4* pS = xqb + (size_t)(cc * 16) * HW_;
#pragma unroll
            for (int k = 0; k < K2_; ++k) {
                const uint4 q0 = qa[k % 5];    // counted vmcnt wait
                const uint4 q1 = qb[k % 5];
                if (k < 4) {                   // refill tap k+5 (same cc)
                    const int a = gaddr[k + 5][pix5];
                    qa[k] = pS[a];
                    qb[k] = pS[HW_ + a];
                }
                const uint2 wp = gw2[k][pix5];
                const f16x2 wt = u2h(wp.x), wbm = u2h(wp.y);
                const float vs0 = __builtin_amdgcn_fdot2(u2h(q0.y), wbm,
                    __builtin_amdgcn_fdot2(u2h(q0.x), wt, 0.f, false), false);
                const float vs1 = __builtin_amdgcn_fdot2(u2h(q0.w), wbm,
                    __builtin_amdgcn_fdot2(u2h(q0.z), wt, 0.f, false), false);
                const float vs2 = __builtin_amdgcn_fdot2(u2h(q1.y), wbm,
                    __builtin_amdgcn_fdot2(u2h(q1.x), wt, 0.f, false), false);
                const float vs3 = __builtin_amdgcn_fdot2(u2h(q1.w), wbm,
                    __builtin_amdgcn_fdot2(u2h(q1.z), wt, 0.f, false), false);
                const unsigned pk0 = h2u(__builtin_amdgcn_cvt_pkrtz(vs0, vs1));
                const unsigned pk1 = h2u(__builtin_amdgcn_cvt_pkrtz(vs2, vs3));
                *(uint2*)(wdst0 + (size_t)k * 32 * 32) = make_uint2(pk0, pk1);
            }
            if (issueA0) {                     // af(cc=0, k=0) bootstrap
#pragma unroll
                for (int mt = 0; mt < 4; ++mt) {
                    const __fp16* ap = wAh +
                        ((size_t)(cc * 16 + wv * 4 + mt) * 512 + (size_t)lane * 8);
                    af0dst[mt] = *(const f16x8*)ap;
                }
            }
            asm volatile("s_waitcnt lgkmcnt(0)" ::: "memory");
            __builtin_amdgcn_s_barrier();
        };

        // ---- MFMA(cc): 9 taps x 8; afC holds af(cc,0); prefetch 1-ahead ----
        auto mfma_phase = [&](int cc, f16x8 (&afC)[4], f16x8 (&afN)[4]) {
#pragma unroll
            for (int k = 0; k < K2_; ++k) {
                // prefetch A for next k (or next cc's k=0) into the other buf
                if (k < 8) {
                    const int kn = k + 1;
#pragma unroll
                    for (int mt = 0; mt < 4; ++mt) {
                        const __fp16* ap = wAh +
                            ((size_t)((kn * 8 + cc) * 16 + wv * 4 + mt) * 512
                             + (size_t)lane * 8);
                        if (k & 1) afC[mt] = *(const f16x8*)ap;
                        else       afN[mt] = *(const f16x8*)ap;
                    }
                } else if (cc < 7) {           // af(cc+1, 0); k==8 even -> afN
#pragma unroll
                    for (int mt = 0; mt < 4; ++mt) {
                        const __fp16* ap = wAh +
                            ((size_t)((cc + 1) * 16 + wv * 4 + mt) * 512
                             + (size_t)lane * 8);
                        afN[mt] = *(const f16x8*)ap;
                    }
                    // then hoist next-cc taps 0-4 gathers (FIFO: after A issue)
                    const uint4* pN = xqb + (size_t)((cc + 1) * 16) * HW_;
#pragma unroll
                    for (int j = 0; j < 5; ++j) {
                        const int a = gaddr[j][pix5];
                        qa[j] = pN[a];
                        qb[j] = pN[HW_ + a];
                    }
                }
#pragma unroll
                for (int nt = 0; nt < 2; ++nt) {
                    const int pr = nt * 16 + lr;
                    const int rs = (2 * lg) ^ (((lr >> 1) & 3) << 1);
                    const f16x8 bv = *(const f16x8*)&btile[k][pr][rs * 4];
#pragma unroll
                    for (int mt = 0; mt < 4; ++mt) {
                        const f16x8 av = (k & 1) ? afN[mt] : afC[mt];
                        acc[mt][nt] = __builtin_amdgcn_mfma_f32_16x16x32_f16(
                            av, bv, acc[mt][nt], 0, 0, 0);
                    }
                }
            }
            asm volatile("s_waitcnt lgkmcnt(0)" ::: "memory");
            __builtin_amdgcn_s_barrier();
        };

        stage(0, afA, true);
        mfma_phase(0, afA, afB);       // leaves af(1,0) in afB
        stage(1, afA, false);
        mfma_phase(1, afB, afA);
        stage(2, afA, false);
        mfma_phase(2, afA, afB);
        stage(3, afA, false);
        mfma_phase(3, afB, afA);
        stage(4, afA, false);
        mfma_phase(4, afA, afB);
        stage(5, afA, false);
        mfma_phase(5, afB, afA);
        stage(6, afA, false);
        mfma_phase(6, afA, afB);
        stage(7, afA, false);
        mfma_phase(7, afB, afA);
    } else {
        // fallback: direct f32 corner loads, plain barriers (correctness only)
        const float* xfb = x + ((size_t)(b * C_) + wv * 8 + ph * 4) * HW_;
        for (int cc = 0; cc < 8; ++cc) {
#pragma unroll
            for (int k = 0; k < K2_; ++k) {
                const int a = gaddr[k][pix5];
                const uint2 wp = gw2[k][pix5];
                const f16x2 wt = u2h(wp.x), wbm = u2h(wp.y);
                const float w00 = (float)wt.x, w01 = (float)wt.y;
                const float w10 = (float)wbm.x, w11 = (float)wbm.y;
                float vs[4];
#pragma unroll
                for (int j = 0; j < 4; ++j) {
                    const float* pl = xfb + (size_t)(cc * 32 + j) * HW_;
                    vs[j] = w00 * pl[a] + w01 * pl[a + 1]
                          + w10 * pl[a + W_] + w11 * pl[a + W_ + 1];
                }
                const unsigned pk0 = h2u(__builtin_amdgcn_cvt_pkrtz(vs[0], vs[1]));
                const unsigned pk1 = h2u(__builtin_amdgcn_cvt_pkrtz(vs[2], vs[3]));
                *(uint2*)(wdst0 + (size_t)k * 32 * 32) = make_uint2(pk0, pk1);
            }
            __syncthreads();
#pragma unroll
            for (int k = 0; k < K2_; ++k) {
                f16x8 af[4];
#pragma unroll
                for (int mt = 0; mt < 4; ++mt) {
                    const __fp16* ap = wAh +
                        ((size_t)((k * 8 + cc) * 16 + wv * 4 + mt) * 512
                         + (size_t)lane * 8);
                    af[mt] = *(const f16x8*)ap;
                }
#pragma unroll
                for (int nt = 0; nt < 2; ++nt) {
                    const int pr = nt * 16 + lr;
                    const int rs = (2 * lg) ^ (((lr >> 1) & 3) << 1);
                    const f16x8 bv = *(const f16x8*)&btile[k][pr][rs * 4];
#pragma unroll
                    for (int mt = 0; mt < 4; ++mt)
                        acc[mt][nt] = __builtin_amdgcn_mfma_f32_16x16x32_f16(
                            af[mt], bv, acc[mt][nt], 0, 0, 0);
                }
            }
            __syncthreads();
        }
    }

    // ---- epilogue: ReLU + store (C/D: col=lane&15 -> pixel, row=lg*4+r -> oc)
    const size_t ob = (size_t)b * C_ * HW_ + (size_t)ho * W_ + hf * 32;
#pragma unroll
    for (int mt = 0; mt < 4; ++mt) {
        const int o0 = wv * 64 + mt * 16 + lg * 4;
#pragma unroll
        for (int nt = 0; nt < 2; ++nt) {
            const int wo = nt * 16 + lr;
#pragma unroll
            for (int r = 0; r < 4; ++r)
                out[ob + (size_t)(o0 + r) * HW_ + wo] =
                    fmaxf(acc[mt][nt][r], 0.f);
        }
    }
}

extern "C" void kernel_launch(void* const* d_in, const int* in_sizes, int n_in,
                              void* d_out, int out_size, void* d_ws, size_t ws_size,
                              hipStream_t stream) {
    const float* x      = (const float*)d_in[0];
    const float* offset = (const float*)d_in[1];
    const float* weight = (const float*)d_in[2];
    float* out          = (float*)d_out;

    const size_t wA_bytes = (size_t)K2_ * C_ * C_ * 2;        // 1.18 MB
    const size_t xq_off   = wA_bytes;                         // 16B-aligned
    const size_t ncell    = (size_t)B_ * (C_ / 2) * HW_;      // 4.19M cells
    const size_t need     = xq_off + ncell * 16;              // ~68.3 MB

    unsigned short* wAp = (unsigned short*)d_ws;
    uint4*          xqp = (uint4*)((char*)d_ws + xq_off);

    wpack_kernel<<<(C_ * C_ * K2_ + 255) / 256, 256, 0, stream>>>(weight, wAp);

    if (ws_size >= need) {
        xq2pack_kernel<<<(int)(ncell / 4 / 256), 256, 0, stream>>>(x, xqp);
        deform_main<0><<<1024, 256, 0, stream>>>(x, xqp, offset, wAp, out);
    } else {
        deform_main<1><<<1024, 256, 0, stream>>>(x, xqp, offset, wAp, out);
    }
}

// Round 12
// 87.825 us; speedup vs baseline: 1.7814x; 1.4709x over previous
//
#include <hip/hip_runtime.h>

// Deformable Conv2D (B=8, C=256, H=W=64, K=3, s=1, p=1) + ReLU via fp16 MFMA.
//
// Round 11: channel-major transpose -> DENSE bilinear gathers.
//  - xpt[b][pix][c4]: 16B cell = fp16 pairs (x[c][p], x[c][p+1]) for 4 ch.
//    One (pixel,tap) sample = 2 dense 1KB loads (top row, bottom row) for
//    ALL 256 channels (vs 18 scattered cell-gathers before): ~28x fewer
//    L1 line-transactions. xpt = 4.19MB/batch = fits batch-pinned XCD L2.
//  - tap-outer phases: MFMA(k) || prefetch A(k+1,0..1) + gathers(k+1) at
//    cc==6 (strict FIFO: counted vmcnt, loads live across barriers),
//    stage(k+1) into double-buffered btile, 1 barrier/tap.
//  - btile[2][64][256] fp16, XOR swizzle chunk^(pix&7): writes+reads ~2-way.

#define B_   8
#define C_   256
#define H_   64
#define W_   64
#define K2_  9
#define HW_  4096
#define NC4  64    // 256 ch / 4 per cell

typedef __fp16 f16x2 __attribute__((ext_vector_type(2)));
typedef __fp16 f16x8 __attribute__((ext_vector_type(8)));
typedef float  f32x4 __attribute__((ext_vector_type(4)));

static __device__ __forceinline__ f16x2 u2h(unsigned u) {
    union { unsigned u; f16x2 h; } v; v.u = u; return v.h;
}
static __device__ __forceinline__ unsigned h2u(f16x2 h) {
    union { unsigned u; f16x2 h; } v; v.h = h; return v.u;
}

// ---- weights -> fp16, MFMA A-fragment lane order (validated r6-r10) ----
__global__ __launch_bounds__(256) void wpack_kernel(
    const float* __restrict__ w, unsigned short* __restrict__ wA) {
    const int t = blockIdx.x * 256 + threadIdx.x;
    if (t >= C_ * C_ * K2_) return;
    const int k = t % 9;
    const int c = (t / 9) & 255;
    const int o = t / (9 * 256);
    const int cc = c >> 5, lg = (c >> 3) & 3, e = c & 7;
    const int t16 = o >> 4, lr = o & 15;
    const int dst = e + 8 * (lr + 16 * (lg + 4 * (t16 + 16 * (cc + 8 * k))));
    const __fp16 h = (__fp16)w[t];
    unsigned short us;
    __builtin_memcpy(&us, &h, 2);
    wA[dst] = us;
}

// ---- x -> channel-major pair cells: xpt[b][pix][c4], cell 16B =
//      {pair(x[4c4+e][p], x[4c4+e][p+1]) for e=0..3} ----
__global__ __launch_bounds__(256) void xptpack_kernel(
    const float* __restrict__ x, uint4* __restrict__ xpt) {
    const int bid = blockIdx.x;              // 512 = b*64 + y
    const int b = bid >> 6, y = bid & 63;
    const int tid = threadIdx.x;
    __shared__ unsigned pr[64][256];         // [col][ch] packed pair (64 KB)

    const float* xb = x + ((size_t)(b * C_ + tid) * H_ + y) * W_;  // ch = tid
#pragma unroll
    for (int i = 0; i < 16; ++i) {
        const int c0 = i * 4;
        const float4 v = *(const float4*)(xb + c0);
        const float nxt = xb[(c0 == 60) ? 63 : c0 + 4];
        pr[c0 + 0][tid] = h2u(__builtin_amdgcn_cvt_pkrtz(v.x, v.y));
        pr[c0 + 1][tid] = h2u(__builtin_amdgcn_cvt_pkrtz(v.y, v.z));
        pr[c0 + 2][tid] = h2u(__builtin_amdgcn_cvt_pkrtz(v.z, v.w));
        pr[c0 + 3][tid] = h2u(__builtin_amdgcn_cvt_pkrtz(v.w, nxt));
    }
    __syncthreads();
    const int lane = tid & 63, wv = tid >> 6;      // 4 waves x 16 cols
    uint4* dst = xpt + ((size_t)b * HW_ + (size_t)y * 64) * NC4;
#pragma unroll
    for (int i = 0; i < 16; ++i) {
        const int col = wv * 16 + i;
        const uint4 cell = *(const uint4*)&pr[col][lane * 4];
        dst[(size_t)col * NC4 + lane] = cell;      // dense 1KB store
    }
}

// MODE 0: dense channel-major gathers, pipelined. MODE 1: f32 fallback.
template<int MODE>
__global__ __launch_bounds__(512, 4) void deform_main(
    const float* __restrict__ x, const uint4* __restrict__ xpt,
    const float* __restrict__ offset, const unsigned short* __restrict__ wA,
    float* __restrict__ out)
{
    const int bid = blockIdx.x;
    const int b = bid & 7, ho = bid >> 3;     // batch -> XCD
    const int tid = threadIdx.x;
    const int lane = tid & 63;                // c4 group in stage; MFMA lane
    const int wv   = tid >> 6;                // wave 0..7 (owns pixels 8wv..)
    const int lr = lane & 15, lg = (lane >> 4) & 3;

    __shared__ unsigned short gaddr[K2_][W_];   // quad base ys*64+xs
    __shared__ uint2 gw2[K2_][W_];              // fp16 pairs (w00,w01),(w10,w11)
    __shared__ alignas(16) unsigned short btile[2][W_][256];  // 64 KB dbuf

    // ---- geometry: 9 taps x 64 pixels (validated r4-r10) ----
    for (int e = tid; e < K2_ * W_; e += 512) {
        const int k = e >> 6, wo = e & 63;
        const float offy = offset[((b * 18 + 2 * k    ) * H_ + ho) * W_ + wo];
        const float offx = offset[((b * 18 + 2 * k + 1) * H_ + ho) * W_ + wo];
        const float py = (float)(k / 3 + ho - 1) + offy;
        const float px = (float)(k % 3 + wo - 1) + offx;
        const float y0f = floorf(py), x0f = floorf(px);
        const int   y0 = (int)y0f,   x0 = (int)x0f;
        const float fy = py - y0f,   fx = px - x0f;
        const float wy0 = (y0 >= 0  && y0 < H_)     ? 1.f - fy : 0.f;
        const float wy1 = (y0 >= -1 && y0 < H_ - 1) ? fy       : 0.f;
        const float wx0 = (x0 >= 0  && x0 < W_)     ? 1.f - fx : 0.f;
        const float wx1 = (x0 >= -1 && x0 < W_ - 1) ? fx       : 0.f;
        const int ys = min(max(y0, 0), H_ - 2);
        const int xs = min(max(x0, 0), W_ - 2);
        const float qy0 = (ys == y0 ? wy0 : 0.f) + (ys == y0 + 1 ? wy1 : 0.f);
        const float qy1 = (ys + 1 == y0 ? wy0 : 0.f) + (ys + 1 == y0 + 1 ? wy1 : 0.f);
        const float qx0 = (xs == x0 ? wx0 : 0.f) + (xs == x0 + 1 ? wx1 : 0.f);
        const float qx1 = (xs + 1 == x0 ? wx0 : 0.f) + (xs + 1 == x0 + 1 ? wx1 : 0.f);
        gaddr[k][wo] = (unsigned short)(ys * W_ + xs);
        gw2[k][wo] = make_uint2(
            h2u(__builtin_amdgcn_cvt_pkrtz(qy0 * qx0, qy0 * qx1)),
            h2u(__builtin_amdgcn_cvt_pkrtz(qy1 * qx0, qy1 * qx1)));
    }
    __syncthreads();

    f32x4 acc[2][4];
#pragma unroll
    for (int m = 0; m < 2; ++m)
#pragma unroll
        for (int n = 0; n < 4; ++n) acc[m][n] = (f32x4)0.f;

    const __fp16* wAh = (const __fp16*)wA;
    const uint4* xptb = xpt + (size_t)b * HW_ * NC4;

    // A-fragment load: slot pair (AS = out tile wv*2, AT = wv*2+1)
#define A_LOAD(k_, cc_, AS, AT) {                                              \
    const __fp16* ap_ = wAh +                                                  \
        (((size_t)((k_) * 8 + (cc_)) * 16 + wv * 2) * 64 + lane) * 8;          \
    AS = *(const f16x8*)ap_;                                                   \
    AT = *(const f16x8*)(ap_ + 512); }

    // dense gather of (tap k_, my pixel j_): all 256 ch top+bottom rows
#define G_ISSUE(k_, j_, QT, QB) {                                              \
    const int qp_ = gaddr[k_][wv * 8 + (j_)];                                  \
    QT = xptb[(size_t)qp_ * NC4 + lane];                                       \
    QB = xptb[(size_t)(qp_ + 64) * NC4 + lane]; }

    // consume gather: 8 fdot2 -> 4 fp16 samples -> swizzled b64 LDS write
#define G_CONSUME(k_, j_, QT, QB, SB) {                                        \
    const int p_ = wv * 8 + (j_);                                              \
    const uint2 wp_ = gw2[k_][p_];                                             \
    const f16x2 wt_ = u2h(wp_.x), wb_ = u2h(wp_.y);                            \
    const float v0_ = __builtin_amdgcn_fdot2(u2h(QT.x), wt_,                   \
        __builtin_amdgcn_fdot2(u2h(QB.x), wb_, 0.f, false), false);            \
    const float v1_ = __builtin_amdgcn_fdot2(u2h(QT.y), wt_,                   \
        __builtin_amdgcn_fdot2(u2h(QB.y), wb_, 0.f, false), false);            \
    const float v2_ = __builtin_amdgcn_fdot2(u2h(QT.z), wt_,                   \
        __builtin_amdgcn_fdot2(u2h(QB.z), wb_, 0.f, false), false);            \
    const float v3_ = __builtin_amdgcn_fdot2(u2h(QT.w), wt_,                   \
        __builtin_amdgcn_fdot2(u2h(QB.w), wb_, 0.f, false), false);            \
    const unsigned pk0_ = h2u(__builtin_amdgcn_cvt_pkrtz(v0_, v1_));           \
    const unsigned pk1_ = h2u(__builtin_amdgcn_cvt_pkrtz(v2_, v3_));           \
    const int phys_ = (lane >> 1) ^ (p_ & 7);                                  \
    *(uint2*)((char*)&btile[SB][p_][0] + phys_ * 16 + (lane & 1) * 8) =        \
        make_uint2(pk0_, pk1_); }

    // one MFMA sub-step: 4 swizzled b128 B-reads + 8 MFMAs
#define MFMA_CC(cc_, MB, AS, AT) {                                             \
    _Pragma("unroll")                                                          \
    for (int nt = 0; nt < 4; ++nt) {                                           \
        const int pix_ = nt * 16 + lr;                                         \
        const int phys_ = ((cc_) * 4 + lg) ^ (pix_ & 7);                       \
        const f16x8 bv_ = *(const f16x8*)                                      \
            ((const char*)&btile[MB][pix_][0] + phys_ * 16);                   \
        acc[0][nt] = __builtin_amdgcn_mfma_f32_16x16x32_f16(                   \
            AS, bv_, acc[0][nt], 0, 0, 0);                                     \
        acc[1][nt] = __builtin_amdgcn_mfma_f32_16x16x32_f16(                   \
            AT, bv_, acc[1][nt], 0, 0, 0);                                     \
    } }

#define STAGE(k_, SB)                                                          \
    G_CONSUME(k_, 0, qT0, qB0, SB) G_ISSUE(k_, 4, qT0, qB0)                    \
    G_CONSUME(k_, 1, qT1, qB1, SB) G_ISSUE(k_, 5, qT1, qB1)                    \
    G_CONSUME(k_, 2, qT2, qB2, SB) G_ISSUE(k_, 6, qT2, qB2)                    \
    G_CONSUME(k_, 3, qT3, qB3, SB) G_ISSUE(k_, 7, qT3, qB3)                    \
    G_CONSUME(k_, 4, qT0, qB0, SB) G_CONSUME(k_, 5, qT1, qB1, SB)              \
    G_CONSUME(k_, 6, qT2, qB2, SB) G_CONSUME(k_, 7, qT3, qB3, SB)

    if constexpr (MODE == 0) {
        uint4 qT0, qB0, qT1, qB1, qT2, qB2, qT3, qB3;
        f16x8 aS0, aT0, aS1, aT1, aS2, aT2, aS3, aT3;

        // prologue: A(0,0..1) then gathers(0, pix 0..3), stage tap 0
        A_LOAD(0, 0, aS0, aT0)
        A_LOAD(0, 1, aS1, aT1)
        G_ISSUE(0, 0, qT0, qB0) G_ISSUE(0, 1, qT1, qB1)
        G_ISSUE(0, 2, qT2, qB2) G_ISSUE(0, 3, qT3, qB3)
        STAGE(0, 0)
        asm volatile("s_waitcnt lgkmcnt(0)" ::: "memory");
        __builtin_amdgcn_s_barrier();

        for (int k = 0; k < K2_; ++k) {
            const int mb = k & 1;
            A_LOAD(k, 2, aS2, aT2) MFMA_CC(0, mb, aS0, aT0)
            A_LOAD(k, 3, aS3, aT3) MFMA_CC(1, mb, aS1, aT1)
            A_LOAD(k, 4, aS0, aT0) MFMA_CC(2, mb, aS2, aT2)
            A_LOAD(k, 5, aS1, aT1) MFMA_CC(3, mb, aS3, aT3)
            A_LOAD(k, 6, aS2, aT2) MFMA_CC(4, mb, aS0, aT0)
            A_LOAD(k, 7, aS3, aT3) MFMA_CC(5, mb, aS1, aT1)
            if (k < K2_ - 1) {        // FIFO: next-tap A first, then gathers
                A_LOAD(k + 1, 0, aS0, aT0)
                A_LOAD(k + 1, 1, aS1, aT1)
                G_ISSUE(k + 1, 0, qT0, qB0) G_ISSUE(k + 1, 1, qT1, qB1)
                G_ISSUE(k + 1, 2, qT2, qB2) G_ISSUE(k + 1, 3, qT3, qB3)
            }
            MFMA_CC(6, mb, aS2, aT2)
            MFMA_CC(7, mb, aS3, aT3)
            if (k < K2_ - 1) {
                const int sb = (k + 1) & 1;
                STAGE(k + 1, sb)
            }
            asm volatile("s_waitcnt lgkmcnt(0)" ::: "memory");
            __builtin_amdgcn_s_barrier();
        }
    } else {
        // fallback: direct f32 corner loads (correctness only)
        for (int k = 0; k < K2_; ++k) {
            const int bb = k & 1;
#pragma unroll
            for (int j = 0; j < 8; ++j) {
                const int p_ = wv * 8 + j;
                const int qp = gaddr[k][p_];
                const uint2 wp_ = gw2[k][p_];
                const f16x2 wt_ = u2h(wp_.x), wb_ = u2h(wp_.y);
                const float w00 = (float)wt_.x, w01 = (float)wt_.y;
                const float w10 = (float)wb_.x, w11 = (float)wb_.y;
                float vv[4];
#pragma unroll
                for (int e2 = 0; e2 < 4; ++e2) {
                    const float* pl = x + ((size_t)(b * C_ + lane * 4 + e2)) * HW_;
                    vv[e2] = w00 * pl[qp] + w01 * pl[qp + 1]
                           + w10 * pl[qp + 64] + w11 * pl[qp + 65];
                }
                const unsigned pk0 = h2u(__builtin_amdgcn_cvt_pkrtz(vv[0], vv[1]));
                const unsigned pk1 = h2u(__builtin_amdgcn_cvt_pkrtz(vv[2], vv[3]));
                const int phys_ = (lane >> 1) ^ (p_ & 7);
                *(uint2*)((char*)&btile[bb][p_][0] + phys_ * 16 + (lane & 1) * 8) =
                    make_uint2(pk0, pk1);
            }
            __syncthreads();
#pragma unroll
            for (int cc = 0; cc < 8; ++cc) {
                f16x8 a0, a1;
                A_LOAD(k, cc, a0, a1)
                MFMA_CC(cc, bb, a0, a1)
            }
            __syncthreads();
        }
    }

    // ---- epilogue: ReLU + store (C/D: col=lane&15 -> pixel, row=lg*4+r -> oc)
    const size_t ob = (size_t)b * C_ * HW_ + (size_t)ho * W_;
#pragma unroll
    for (int mt = 0; mt < 2; ++mt) {
        const int o0 = wv * 32 + mt * 16 + lg * 4;
#pragma unroll
        for (int nt = 0; nt < 4; ++nt) {
            const int wo = nt * 16 + lr;
#pragma unroll
            for (int r = 0; r < 4; ++r)
                out[ob + (size_t)(o0 + r) * HW_ + wo] =
                    fmaxf(acc[mt][nt][r], 0.f);
        }
    }
#undef A_LOAD
#undef G_ISSUE
#undef G_CONSUME
#undef MFMA_CC
#undef STAGE
}

extern "C" void kernel_launch(void* const* d_in, const int* in_sizes, int n_in,
                              void* d_out, int out_size, void* d_ws, size_t ws_size,
                              hipStream_t stream) {
    const float* x      = (const float*)d_in[0];
    const float* offset = (const float*)d_in[1];
    const float* weight = (const float*)d_in[2];
    float* out          = (float*)d_out;

    const size_t wA_bytes = (size_t)K2_ * C_ * C_ * 2;        // 1.18 MB
    const size_t xp_off   = wA_bytes;                         // 16B-aligned
    const size_t xp_bytes = (size_t)B_ * HW_ * NC4 * 16;      // 33.6 MB
    const size_t need     = xp_off + xp_bytes;                // ~34.7 MB

    unsigned short* wAp = (unsigned short*)d_ws;
    uint4*          xpp = (uint4*)((char*)d_ws + xp_off);

    wpack_kernel<<<(C_ * C_ * K2_ + 255) / 256, 256, 0, stream>>>(weight, wAp);

    if (ws_size >= need) {
        xptpack_kernel<<<B_ * H_, 256, 0, stream>>>(x, xpp);
        deform_main<0><<<512, 512, 0, stream>>>(x, xpp, offset, wAp, out);
    } else {
        deform_main<1><<<512, 512, 0, stream>>>(x, xpp, offset, wAp, out);
    }
}